// Round 14
// baseline (297.394 us; speedup 1.0000x reference)
//
#include <hip/hip_runtime.h>
#include <hip/hip_bf16.h>
#include <math.h>

#define N_TOK 4096
#define D_MODEL 1024
#define NHEAD 8
#define DKQ 16
#define DVH 64
#define QGW 80   // DK+DV columns per head
#define QGN 640  // H * 80
#define HD  512  // H * DV
#define TI  32   // attention: i-rows per tile
#define DC  64   // attention: j-chunk width
#define NCH_MAX 5

typedef __attribute__((ext_vector_type(8))) short short8;
typedef __attribute__((ext_vector_type(4))) float f32x4;

#define GLOAD_LDS16(gp, lp) \
  __builtin_amdgcn_global_load_lds((const __attribute__((address_space(1))) void*)(gp), \
                                   (__attribute__((address_space(3))) void*)(lp), 16, 0, 0)

// ---------------------------------------------------------------------------
// pack: tokens fp32->bf16 cast (grid-stride, blocks [0,1024)) + 3 weight
// transpose+casts (blocks [1024, 2816)). Block 0 also zeroes the finish
// counters used by the attention kernel's last-finisher reduction.
// ---------------------------------------------------------------------------
__global__ __launch_bounds__(256) void pack_kernel(
    const float* __restrict__ tokens, const float* __restrict__ w_qg,
    const float* __restrict__ w_kv, const float* __restrict__ w_out,
    __hip_bfloat16* __restrict__ tokB, __hip_bfloat16* __restrict__ wqgT,
    __hip_bfloat16* __restrict__ wkvT, __hip_bfloat16* __restrict__ woutT,
    int* __restrict__ counters)
{
    __shared__ float tile[32][33];
    int b = blockIdx.x;
    int t = threadIdx.x;

    if (b < 1024) {                       // tokens cast, 4 float4 per thread
        if (b == 0) {                     // zero finish counters (1024 ints)
            #pragma unroll
            for (int z = 0; z < 4; ++z) counters[t + z * 256] = 0;
        }
        #pragma unroll
        for (int it = 0; it < 4; ++it) {
            int i4 = b * 256 + t + it * 262144;
            float4 v = ((const float4*)tokens)[i4];
            __hip_bfloat16 o[4] = { __float2bfloat16(v.x), __float2bfloat16(v.y),
                                    __float2bfloat16(v.z), __float2bfloat16(v.w) };
            ((ushort4*)tokB)[i4] = *(const ushort4*)o;
        }
        return;
    }

    const float* in; __hip_bfloat16* outp; int R, C, tb;
    b -= 1024;
    if (b < 640)       { in = w_qg;  outp = wqgT;  R = 1024; C = 640;  tb = b; }
    else if (b < 1280) { in = w_kv;  outp = wkvT;  R = 1024; C = 640;  tb = b - 640; }
    else               { in = w_out; outp = woutT; R = 512;  C = 1024; tb = b - 1280; }
    int ctiles = C / 32;
    int bx = (tb % ctiles) * 32;
    int by = (tb / ctiles) * 32;
    int tx = t & 31, ty = t >> 5;

    #pragma unroll
    for (int j = 0; j < 32; j += 8)
        tile[j + ty][tx] = in[(size_t)(by + j + ty) * C + bx + tx];
    __syncthreads();
    #pragma unroll
    for (int j = 0; j < 32; j += 8)
        outp[(size_t)(bx + j + ty) * R + by + tx] =
            __float2bfloat16(tile[tx][j + ty]);
}

// ---------------------------------------------------------------------------
// bf16 MFMA GEMM, 128x64 tile, BK=64 double-buffered, XCD-chunked swizzle.
// ---------------------------------------------------------------------------
__global__ __launch_bounds__(256) void gemm_mfma(
    const __hip_bfloat16* __restrict__ A,
    const __hip_bfloat16* __restrict__ Bt0, float* __restrict__ C0,
    const __hip_bfloat16* __restrict__ Bt1, float* __restrict__ C1,
    int Nb, int K, int ntiles_n)
{
    __shared__ __hip_bfloat16 As[2][2][128 * 32];   // 32 KB
    __shared__ __hip_bfloat16 Bs[2][2][64 * 32];    // 16 KB

    int t = threadIdx.x;
    int l = t & 63;
    int w = t >> 6;
    int wr = w >> 1, wc = w & 1;

    // XCD-chunked bijective remap (m204): hw-id -> work-id
    int nwg  = gridDim.x * gridDim.y;
    int flat = blockIdx.y * gridDim.x + blockIdx.x;
    int q    = nwg >> 3;                      // nwg / 8, nwg % 8 == 0
    int rid  = (flat & 7) * q + (flat >> 3);
    int bnt  = rid % gridDim.x;
    int bmt  = rid / gridDim.x;

    const __hip_bfloat16* Bt = Bt0;
    float* C = C0;
    if (bnt >= ntiles_n) { Bt = Bt1; C = C1; bnt -= ntiles_n; }
    int bm = bmt * 128;
    int bn = bnt * 64;

    int srow = t >> 2;
    int skc  = (t & 3) * 8;
    const __hip_bfloat16* ga0 = A + (size_t)(bm + srow) * K + skc;
    const __hip_bfloat16* ga1 = A + (size_t)(bm + 64 + srow) * K + skc;
    const __hip_bfloat16* gb  = Bt + (size_t)(bn + srow) * K + skc;
    int ldst = (t & ~63) * 8;           // wave-uniform LDS base (elems)

#define STAGE(buf, k0) do { \
    GLOAD_LDS16(ga0 + (k0),      &As[buf][0][ldst]); \
    GLOAD_LDS16(ga1 + (k0),      &As[buf][0][2048 + ldst]); \
    GLOAD_LDS16(gb  + (k0),      &Bs[buf][0][ldst]); \
    GLOAD_LDS16(ga0 + (k0) + 32, &As[buf][1][ldst]); \
    GLOAD_LDS16(ga1 + (k0) + 32, &As[buf][1][2048 + ldst]); \
    GLOAD_LDS16(gb  + (k0) + 32, &Bs[buf][1][ldst]); } while (0)

    f32x4 acc[4][2] = {};

    int aro = (wr * 64 + (l & 15)) * 32 + (l >> 4) * 8;
    int bro = (wc * 32 + (l & 15)) * 32 + (l >> 4) * 8;

    int nk = K >> 6;                    // K / 64
    STAGE(0, 0);                        // prologue
    __syncthreads();

    int cur = 0;
    for (int it = 0; it < nk; ++it) {
        if (it + 1 < nk) STAGE(cur ^ 1, (it + 1) << 6);   // prefetch next

        #pragma unroll
        for (int kk = 0; kk < 2; ++kk) {
            short8 af[4], bf[2];
            #pragma unroll
            for (int m = 0; m < 4; ++m)
                af[m] = *(const short8*)&As[cur][kk][aro + m * 16 * 32];
            #pragma unroll
            for (int n = 0; n < 2; ++n)
                bf[n] = *(const short8*)&Bs[cur][kk][bro + n * 16 * 32];

            #pragma unroll
            for (int m = 0; m < 4; ++m)
                #pragma unroll
                for (int n = 0; n < 2; ++n)
                    acc[m][n] = __builtin_amdgcn_mfma_f32_16x16x32_bf16(
                                    af[m], bf[n], acc[m][n], 0, 0, 0);
        }
        __syncthreads();                // drains prefetch; next buf ready
        cur ^= 1;
    }
#undef STAGE

    int crow = bm + wr * 64 + (l >> 4) * 4;
    int ccol = bn + wc * 32 + (l & 15);
    #pragma unroll
    for (int m = 0; m < 4; ++m)
        #pragma unroll
        for (int n = 0; n < 2; ++n)
            #pragma unroll
            for (int j = 0; j < 4; ++j)
                C[(size_t)(crow + m * 16 + j) * Nb + ccol + n * 16] = acc[m][n][j];
}

// ---------------------------------------------------------------------------
// Chunk-parallel banded attention with fused normalization, band-trim, and
// LAST-FINISHER epilogue: nch==1 blocks finalize inline; nch>=2 blocks write
// a Ypart partial, bump a per-(h,tile) counter (acq-rel, device scope), and
// the last one to finish sums all slots IN FIXED ORDER and finalizes.
// ---------------------------------------------------------------------------
__global__ __launch_bounds__(256) void attn_chunk_kernel(
    const float* __restrict__ qg, const float* __restrict__ kv,
    const float* __restrict__ log_window, const float* __restrict__ log_r,
    const float* __restrict__ log_hscale,
    float* __restrict__ Ypart, __hip_bfloat16* __restrict__ Yb,
    int* __restrict__ counters)
{
    int bid = blockIdx.x;                 // h*(128*NCH_MAX) + tile*NCH_MAX + slot
    int h    = bid / (128 * NCH_MAX);
    int rem  = bid - h * (128 * NCH_MAX);
    int tile = rem / NCH_MAX;
    int slot = rem - tile * NCH_MAX;
    int i0 = tile * TI;
    int t = threadIdx.x;

    float w = expf(log_window[h]) + 1.f;
    float r = expf(log_r[h]) + 1.f;
    int dmax = (int)ceilf(w) - 1;
    int jstart = i0 - dmax; if (jstart < 0) jstart = 0;
    int nch = (i0 + TI - jstart + DC - 1) / DC;
    if (slot >= nch) return;
    int j0 = jstart + slot * DC;

    int jc_hi  = min(DC, i0 + TI - j0);   // rows >= jc_hi are outside every band
    int jc_pad = (jc_hi + 3) & ~3;        // pad to float4 PV groups
    int g4_hi  = jc_pad >> 2;

    __shared__ float Q_lds[TI][16];
    __shared__ float K_lds[DC][16];
    __shared__ float V_lds[DC][DVH];
    __shared__ float att_lds[TI][68];
    __shared__ float soft_lds[288];
    __shared__ int lastflag;

    const float PI = 3.14159265358979f;
    for (int d = t; d <= dmax; d += 256)
        soft_lds[d] = 0.5f * (cosf(PI * (float)d / w) + 1.f);

    if (t < TI * 4) {
        int iq = t >> 2, c = (t & 3) * 4;
        float4 qv = *(const float4*)(qg + (size_t)(i0 + iq) * QGN + h * QGW + c);
        float s = qv.x*qv.x + qv.y*qv.y + qv.z*qv.z + qv.w*qv.w;
        s += __shfl_xor(s, 1); s += __shfl_xor(s, 2);
        float inv = 1.f / fmaxf(sqrtf(s), 1e-12f);
        qv.x *= inv; qv.y *= inv; qv.z *= inv; qv.w *= inv;
        *(float4*)&Q_lds[iq][c] = qv;
    }
    // K stage + normalize (only rows < jc_hi are meaningful)
    {
        int jr = t >> 2, c = (t & 3) * 4;
        int j = j0 + jr;
        if (jr < jc_hi) {
            float4 kx = make_float4(0.f, 0.f, 0.f, 0.f);
            if (j < N_TOK)
                kx = *(const float4*)(kv + (size_t)j * QGN + h * QGW + c);
            float s = kx.x*kx.x + kx.y*kx.y + kx.z*kx.z + kx.w*kx.w;
            s += __shfl_xor(s, 1); s += __shfl_xor(s, 2);
            float inv = 1.f / fmaxf(sqrtf(s), 1e-12f);
            kx.x *= inv; kx.y *= inv; kx.z *= inv; kx.w *= inv;
            *(float4*)&K_lds[jr][c] = kx;
        }
    }
    // V stage + normalize (rows < jc_pad so PV partial groups read defined data)
    #pragma unroll
    for (int kk = 0; kk < 4; ++kk) {
        int f = t + kk * 256;
        int jc = f >> 4, c = (f & 15) * 4;
        int j = j0 + jc;
        if (jc < jc_pad) {
            float4 vx = make_float4(0.f, 0.f, 0.f, 0.f);
            if (j < N_TOK)
                vx = *(const float4*)(kv + (size_t)j * QGN + h * QGW + DKQ + c);
            float s = vx.x*vx.x + vx.y*vx.y + vx.z*vx.z + vx.w*vx.w;
            s += __shfl_xor(s, 1); s += __shfl_xor(s, 2);
            s += __shfl_xor(s, 4); s += __shfl_xor(s, 8);
            float inv = 1.f / fmaxf(sqrtf(s), 1e-12f);
            vx.x *= inv; vx.y *= inv; vx.z *= inv; vx.w *= inv;
            *(float4*)&V_lds[jc][c] = vx;
        }
    }
    __syncthreads();

    int i_loc = t & 31;
    int jgrp  = t >> 5;
    int i_glob = i0 + i_loc;
    float q[16];
    #pragma unroll
    for (int c = 0; c < 16; ++c) q[c] = Q_lds[i_loc][c];

    #pragma unroll
    for (int jj = 0; jj < 8; ++jj) {
        int jc = jgrp * 8 + jj;
        if (jc >= jc_pad) break;
        int j = j0 + jc;
        int d = i_glob - j;
        float sim = 0.f;
        #pragma unroll
        for (int c4 = 0; c4 < 4; ++c4) {
            float4 kk4 = *(const float4*)&K_lds[jc][c4 * 4];
            sim += q[c4*4+0]*kk4.x + q[c4*4+1]*kk4.y
                 + q[c4*4+2]*kk4.z + q[c4*4+3]*kk4.w;
        }
        float a = fmaxf(1.f - r * (1.f - sim), 0.f);
        int dc = min(max(d, 0), dmax);
        bool valid = (d >= 0) && (d <= dmax);
        att_lds[i_loc][jc] = valid ? a * a * soft_lds[dc] : 0.f;
    }
    __syncthreads();

    int wv = t >> 6, ihalf = (t >> 5) & 1, dvp = t & 31;
    int ib = wv * 8 + ihalf * 4;
    float acc[4][2] = {};

    for (int g4 = 0; g4 < g4_hi; ++g4) {
        int jc0 = g4 * 4;
        float4 am[4];
        #pragma unroll
        for (int m = 0; m < 4; ++m)
            am[m] = *(const float4*)&att_lds[ib + m][jc0];
        float2 v0 = *(const float2*)&V_lds[jc0 + 0][dvp * 2];
        float2 v1 = *(const float2*)&V_lds[jc0 + 1][dvp * 2];
        float2 v2 = *(const float2*)&V_lds[jc0 + 2][dvp * 2];
        float2 v3 = *(const float2*)&V_lds[jc0 + 3][dvp * 2];
        #pragma unroll
        for (int m = 0; m < 4; ++m) {
            acc[m][0] += am[m].x * v0.x + am[m].y * v1.x
                       + am[m].z * v2.x + am[m].w * v3.x;
            acc[m][1] += am[m].x * v0.y + am[m].y * v1.y
                       + am[m].z * v2.y + am[m].w * v3.y;
        }
    }

    if (nch == 1) {
        // single-chunk: finalize inline (unchanged from R13)
        float hs = expf(log_hscale[h]);
        #pragma unroll
        for (int m = 0; m < 4; ++m) {
            float ss = acc[m][0]*acc[m][0] + acc[m][1]*acc[m][1];
            #pragma unroll
            for (int off = 16; off; off >>= 1) ss += __shfl_xor(ss, off);
            float norm = sqrtf(ss);
            float scale = tanhf(norm) / fmaxf(norm, 1e-12f);
            int i = i0 + ib + m;
            float2 g2 = *(const float2*)(qg + (size_t)i * QGN + h * QGW + DKQ + dvp * 2);
            float gate0 = tanhf(g2.x / (1.f + expf(-g2.x)));
            float gate1 = tanhf(g2.y / (1.f + expf(-g2.y)));
            __hip_bfloat16 ob[2] = { __float2bfloat16(acc[m][0] * scale * gate0 * hs),
                                     __float2bfloat16(acc[m][1] * scale * gate1 * hs) };
            *(ushort2*)(Yb + (size_t)i * HD + h * DVH + dvp * 2) = *(const ushort2*)ob;
        }
        return;
    }

    // multi-chunk: write partial, then last finisher sums in fixed slot order
    #pragma unroll
    for (int m = 0; m < 4; ++m) {
        int i = i0 + ib + m;
        float2 st = make_float2(acc[m][0], acc[m][1]);
        *(float2*)(Ypart + ((size_t)slot * N_TOK + i) * HD + h * DVH + dvp * 2) = st;
    }

    __threadfence();                      // make partial visible device-wide
    if (t == 0) {
        int prev = __hip_atomic_fetch_add(&counters[h * 128 + tile], 1,
                                          __ATOMIC_ACQ_REL,
                                          __HIP_MEMORY_SCOPE_AGENT);
        lastflag = (prev == nch - 1);
    }
    __syncthreads();
    if (!lastflag) return;
    __threadfence();                      // acquire side: see others' partials

    float hs = expf(log_hscale[h]);
    int wv2 = t >> 6, lane = t & 63;
    for (int mrow = 0; mrow < 8; ++mrow) {    // 4 waves x 8 rows = 32 rows
        int i = i0 + wv2 * 8 + mrow;
        size_t base = (size_t)i * HD + h * DVH + lane;
        float a = 0.f;
        for (int c = 0; c < nch; ++c)         // fixed order -> deterministic
            a += Ypart[(size_t)c * N_TOK * HD + base];

        float g = qg[(size_t)i * QGN + h * QGW + DKQ + lane];
        float gate = tanhf(g / (1.f + expf(-g)));

        float ss = a * a;
        #pragma unroll
        for (int off = 32; off; off >>= 1) ss += __shfl_xor(ss, off);
        float norm = sqrtf(ss);
        float scale = tanhf(norm) / fmaxf(norm, 1e-12f);

        Yb[(size_t)i * HD + h * DVH + lane] =
            __float2bfloat16(a * scale * gate * hs);
    }
}

// ---------------------------------------------------------------------------
extern "C" void kernel_launch(void* const* d_in, const int* in_sizes, int n_in,
                              void* d_out, int out_size, void* d_ws, size_t ws_size,
                              hipStream_t stream)
{
    const float* tokens     = (const float*)d_in[0];
    const float* w_qg       = (const float*)d_in[1];
    const float* w_kv       = (const float*)d_in[2];
    const float* w_out      = (const float*)d_in[3];
    const float* log_window = (const float*)d_in[4];
    const float* log_r      = (const float*)d_in[5];
    const float* log_hscale = (const float*)d_in[6];
    float* out = (float*)d_out;

    char* ws = (char*)d_ws;
    float* qg = (float*)ws;            ws += (size_t)N_TOK * QGN * 4;
    float* kv = (float*)ws;            ws += (size_t)N_TOK * QGN * 4;
    __hip_bfloat16* tokB  = (__hip_bfloat16*)ws; ws += (size_t)N_TOK * D_MODEL * 2;
    __hip_bfloat16* wqgT  = (__hip_bfloat16*)ws; ws += (size_t)QGN * D_MODEL * 2;
    __hip_bfloat16* wkvT  = (__hip_bfloat16*)ws; ws += (size_t)QGN * D_MODEL * 2;
    __hip_bfloat16* woutT = (__hip_bfloat16*)ws; ws += (size_t)D_MODEL * HD * 2;
    __hip_bfloat16* Yb    = (__hip_bfloat16*)ws; ws += (size_t)N_TOK * HD * 2;
    float* Ypart = (float*)ws;         ws += (size_t)NCH_MAX * N_TOK * HD * 4;
    int* counters = (int*)ws;          ws += (size_t)NHEAD * 128 * 4;

    // 0) pack: tokens cast + weight transposes + counter zeroing
    pack_kernel<<<2816, 256, 0, stream>>>(tokens, w_qg, w_kv, w_out,
                                          tokB, wqgT, wkvT, woutT, counters);
    // 1) qg / kv projection (dual-B, BN=64 -> 640 blocks, XCD-swizzled)
    {
        dim3 grid(2 * (QGN / 64), N_TOK / 128);
        gemm_mfma<<<grid, 256, 0, stream>>>(tokB, wqgT, qg, wkvT, kv,
                                            QGN, D_MODEL, QGN / 64);
    }
    // 2) chunk-parallel attention with last-finisher epilogue (no epi node)
    attn_chunk_kernel<<<NHEAD * (N_TOK / TI) * NCH_MAX, 256, 0, stream>>>(
        qg, kv, log_window, log_r, log_hscale, Ypart, Yb, counters);
    // 3) out = Y @ w_out (512 blocks, XCD-swizzled)
    {
        dim3 grid(D_MODEL / 64, N_TOK / 128);
        gemm_mfma<<<grid, 256, 0, stream>>>(Yb, woutT, out, woutT, out,
                                            D_MODEL, HD, D_MODEL / 64);
    }
}

// Round 15
// 78.277 us; speedup vs baseline: 3.7993x; 3.7993x over previous
//
#include <hip/hip_runtime.h>
#include <hip/hip_bf16.h>
#include <math.h>

#define N_TOK 4096
#define D_MODEL 1024
#define NHEAD 8
#define DKQ 16
#define DVH 64
#define QGW 80   // DK+DV columns per head
#define QGN 640  // H * 80
#define HD  512  // H * DV
#define TI  32   // attention: i-rows per tile
#define DC  64   // attention: j-chunk width
#define NCH_MAX 5
#define EPI_UNITS (3 * N_TOK / 4)   // h in {5,6,7}, 4 rows per unit

typedef __attribute__((ext_vector_type(8))) short short8;
typedef __attribute__((ext_vector_type(4))) float f32x4;

#define GLOAD_LDS16(gp, lp) \
  __builtin_amdgcn_global_load_lds((const __attribute__((address_space(1))) void*)(gp), \
                                   (__attribute__((address_space(3))) void*)(lp), 16, 0, 0)

// ---------------------------------------------------------------------------
// pack: tokens fp32->bf16 cast (grid-stride, blocks [0,1024)) + 3 weight
// transpose+casts (blocks [1024, 2816)).
// ---------------------------------------------------------------------------
__global__ __launch_bounds__(256) void pack_kernel(
    const float* __restrict__ tokens, const float* __restrict__ w_qg,
    const float* __restrict__ w_kv, const float* __restrict__ w_out,
    __hip_bfloat16* __restrict__ tokB, __hip_bfloat16* __restrict__ wqgT,
    __hip_bfloat16* __restrict__ wkvT, __hip_bfloat16* __restrict__ woutT)
{
    __shared__ float tile[32][33];
    int b = blockIdx.x;
    int t = threadIdx.x;

    if (b < 1024) {                       // tokens cast, 4 float4 per thread
        #pragma unroll
        for (int it = 0; it < 4; ++it) {
            int i4 = b * 256 + t + it * 262144;
            float4 v = ((const float4*)tokens)[i4];
            __hip_bfloat16 o[4] = { __float2bfloat16(v.x), __float2bfloat16(v.y),
                                    __float2bfloat16(v.z), __float2bfloat16(v.w) };
            ((ushort4*)tokB)[i4] = *(const ushort4*)o;
        }
        return;
    }

    const float* in; __hip_bfloat16* outp; int R, C, tb;
    b -= 1024;
    if (b < 640)       { in = w_qg;  outp = wqgT;  R = 1024; C = 640;  tb = b; }
    else if (b < 1280) { in = w_kv;  outp = wkvT;  R = 1024; C = 640;  tb = b - 640; }
    else               { in = w_out; outp = woutT; R = 512;  C = 1024; tb = b - 1280; }
    int ctiles = C / 32;
    int bx = (tb % ctiles) * 32;
    int by = (tb / ctiles) * 32;
    int tx = t & 31, ty = t >> 5;

    #pragma unroll
    for (int j = 0; j < 32; j += 8)
        tile[j + ty][tx] = in[(size_t)(by + j + ty) * C + bx + tx];
    __syncthreads();
    #pragma unroll
    for (int j = 0; j < 32; j += 8)
        outp[(size_t)(bx + j + ty) * R + by + tx] =
            __float2bfloat16(tile[tx][j + ty]);
}

// ---------------------------------------------------------------------------
// bf16 MFMA GEMM, 128x64 tile, BK=64 double-buffered, XCD-chunked swizzle:
// blocks sharing an A-panel (same bm) are concentrated on one XCD so the
// 256KB panel stays in that XCD's L2. Requires (gridDim.x*gridDim.y)%8==0.
// ---------------------------------------------------------------------------
__global__ __launch_bounds__(256) void gemm_mfma(
    const __hip_bfloat16* __restrict__ A,
    const __hip_bfloat16* __restrict__ Bt0, float* __restrict__ C0,
    const __hip_bfloat16* __restrict__ Bt1, float* __restrict__ C1,
    int Nb, int K, int ntiles_n)
{
    __shared__ __hip_bfloat16 As[2][2][128 * 32];   // 32 KB
    __shared__ __hip_bfloat16 Bs[2][2][64 * 32];    // 16 KB

    int t = threadIdx.x;
    int l = t & 63;
    int w = t >> 6;
    int wr = w >> 1, wc = w & 1;

    // XCD-chunked bijective remap (m204): hw-id -> work-id
    int nwg  = gridDim.x * gridDim.y;
    int flat = blockIdx.y * gridDim.x + blockIdx.x;
    int q    = nwg >> 3;                      // nwg / 8, nwg % 8 == 0
    int rid  = (flat & 7) * q + (flat >> 3);
    int bnt  = rid % gridDim.x;
    int bmt  = rid / gridDim.x;

    const __hip_bfloat16* Bt = Bt0;
    float* C = C0;
    if (bnt >= ntiles_n) { Bt = Bt1; C = C1; bnt -= ntiles_n; }
    int bm = bmt * 128;
    int bn = bnt * 64;

    int srow = t >> 2;
    int skc  = (t & 3) * 8;
    const __hip_bfloat16* ga0 = A + (size_t)(bm + srow) * K + skc;
    const __hip_bfloat16* ga1 = A + (size_t)(bm + 64 + srow) * K + skc;
    const __hip_bfloat16* gb  = Bt + (size_t)(bn + srow) * K + skc;
    int ldst = (t & ~63) * 8;           // wave-uniform LDS base (elems)

#define STAGE(buf, k0) do { \
    GLOAD_LDS16(ga0 + (k0),      &As[buf][0][ldst]); \
    GLOAD_LDS16(ga1 + (k0),      &As[buf][0][2048 + ldst]); \
    GLOAD_LDS16(gb  + (k0),      &Bs[buf][0][ldst]); \
    GLOAD_LDS16(ga0 + (k0) + 32, &As[buf][1][ldst]); \
    GLOAD_LDS16(ga1 + (k0) + 32, &As[buf][1][2048 + ldst]); \
    GLOAD_LDS16(gb  + (k0) + 32, &Bs[buf][1][ldst]); } while (0)

    f32x4 acc[4][2] = {};

    int aro = (wr * 64 + (l & 15)) * 32 + (l >> 4) * 8;
    int bro = (wc * 32 + (l & 15)) * 32 + (l >> 4) * 8;

    int nk = K >> 6;                    // K / 64
    STAGE(0, 0);                        // prologue
    __syncthreads();

    int cur = 0;
    for (int it = 0; it < nk; ++it) {
        if (it + 1 < nk) STAGE(cur ^ 1, (it + 1) << 6);   // prefetch next

        #pragma unroll
        for (int kk = 0; kk < 2; ++kk) {
            short8 af[4], bf[2];
            #pragma unroll
            for (int m = 0; m < 4; ++m)
                af[m] = *(const short8*)&As[cur][kk][aro + m * 16 * 32];
            #pragma unroll
            for (int n = 0; n < 2; ++n)
                bf[n] = *(const short8*)&Bs[cur][kk][bro + n * 16 * 32];

            #pragma unroll
            for (int m = 0; m < 4; ++m)
                #pragma unroll
                for (int n = 0; n < 2; ++n)
                    acc[m][n] = __builtin_amdgcn_mfma_f32_16x16x32_bf16(
                                    af[m], bf[n], acc[m][n], 0, 0, 0);
        }
        __syncthreads();                // drains prefetch; next buf ready
        cur ^= 1;
    }
#undef STAGE

    int crow = bm + wr * 64 + (l >> 4) * 4;
    int ccol = bn + wc * 32 + (l & 15);
    #pragma unroll
    for (int m = 0; m < 4; ++m)
        #pragma unroll
        for (int n = 0; n < 2; ++n)
            #pragma unroll
            for (int j = 0; j < 4; ++j)
                C[(size_t)(crow + m * 16 + j) * Nb + ccol + n * 16] = acc[m][n][j];
}

// ---------------------------------------------------------------------------
// Chunk-parallel banded attention, fused normalization; band-trimmed staging
// and PV (jc_hi); fused epilogue when nch==1, else partial to Ypart.
// ---------------------------------------------------------------------------
__global__ __launch_bounds__(256) void attn_chunk_kernel(
    const float* __restrict__ qg, const float* __restrict__ kv,
    const float* __restrict__ log_window, const float* __restrict__ log_r,
    const float* __restrict__ log_hscale,
    float* __restrict__ Ypart, __hip_bfloat16* __restrict__ Yb)
{
    int bid = blockIdx.x;                 // h*(128*NCH_MAX) + tile*NCH_MAX + slot
    int h    = bid / (128 * NCH_MAX);
    int rem  = bid - h * (128 * NCH_MAX);
    int tile = rem / NCH_MAX;
    int slot = rem - tile * NCH_MAX;
    int i0 = tile * TI;
    int t = threadIdx.x;

    float w = expf(log_window[h]) + 1.f;
    float r = expf(log_r[h]) + 1.f;
    int dmax = (int)ceilf(w) - 1;
    int jstart = i0 - dmax; if (jstart < 0) jstart = 0;
    int nch = (i0 + TI - jstart + DC - 1) / DC;
    if (slot >= nch) return;
    int j0 = jstart + slot * DC;

    int jc_hi  = min(DC, i0 + TI - j0);   // rows >= jc_hi are outside every band
    int jc_pad = (jc_hi + 3) & ~3;        // pad to float4 PV groups
    int g4_hi  = jc_pad >> 2;

    __shared__ float Q_lds[TI][16];
    __shared__ float K_lds[DC][16];
    __shared__ float V_lds[DC][DVH];
    __shared__ float att_lds[TI][68];
    __shared__ float soft_lds[288];

    const float PI = 3.14159265358979f;
    for (int d = t; d <= dmax; d += 256)
        soft_lds[d] = 0.5f * (cosf(PI * (float)d / w) + 1.f);

    if (t < TI * 4) {
        int iq = t >> 2, c = (t & 3) * 4;
        float4 qv = *(const float4*)(qg + (size_t)(i0 + iq) * QGN + h * QGW + c);
        float s = qv.x*qv.x + qv.y*qv.y + qv.z*qv.z + qv.w*qv.w;
        s += __shfl_xor(s, 1); s += __shfl_xor(s, 2);
        float inv = 1.f / fmaxf(sqrtf(s), 1e-12f);
        qv.x *= inv; qv.y *= inv; qv.z *= inv; qv.w *= inv;
        *(float4*)&Q_lds[iq][c] = qv;
    }
    // K stage + normalize (only rows < jc_hi are meaningful)
    {
        int jr = t >> 2, c = (t & 3) * 4;
        int j = j0 + jr;
        if (jr < jc_hi) {
            float4 kx = make_float4(0.f, 0.f, 0.f, 0.f);
            if (j < N_TOK)
                kx = *(const float4*)(kv + (size_t)j * QGN + h * QGW + c);
            float s = kx.x*kx.x + kx.y*kx.y + kx.z*kx.z + kx.w*kx.w;
            s += __shfl_xor(s, 1); s += __shfl_xor(s, 2);
            float inv = 1.f / fmaxf(sqrtf(s), 1e-12f);
            kx.x *= inv; kx.y *= inv; kx.z *= inv; kx.w *= inv;
            *(float4*)&K_lds[jr][c] = kx;
        }
    }
    // V stage + normalize (rows < jc_pad so PV partial groups read defined data)
    #pragma unroll
    for (int kk = 0; kk < 4; ++kk) {
        int f = t + kk * 256;
        int jc = f >> 4, c = (f & 15) * 4;
        int j = j0 + jc;
        if (jc < jc_pad) {
            float4 vx = make_float4(0.f, 0.f, 0.f, 0.f);
            if (j < N_TOK)
                vx = *(const float4*)(kv + (size_t)j * QGN + h * QGW + DKQ + c);
            float s = vx.x*vx.x + vx.y*vx.y + vx.z*vx.z + vx.w*vx.w;
            s += __shfl_xor(s, 1); s += __shfl_xor(s, 2);
            s += __shfl_xor(s, 4); s += __shfl_xor(s, 8);
            float inv = 1.f / fmaxf(sqrtf(s), 1e-12f);
            vx.x *= inv; vx.y *= inv; vx.z *= inv; vx.w *= inv;
            *(float4*)&V_lds[jc][c] = vx;
        }
    }
    __syncthreads();

    int i_loc = t & 31;
    int jgrp  = t >> 5;
    int i_glob = i0 + i_loc;
    float q[16];
    #pragma unroll
    for (int c = 0; c < 16; ++c) q[c] = Q_lds[i_loc][c];

    #pragma unroll
    for (int jj = 0; jj < 8; ++jj) {
        int jc = jgrp * 8 + jj;
        if (jc >= jc_pad) break;
        int j = j0 + jc;
        int d = i_glob - j;
        float sim = 0.f;
        #pragma unroll
        for (int c4 = 0; c4 < 4; ++c4) {
            float4 kk4 = *(const float4*)&K_lds[jc][c4 * 4];
            sim += q[c4*4+0]*kk4.x + q[c4*4+1]*kk4.y
                 + q[c4*4+2]*kk4.z + q[c4*4+3]*kk4.w;
        }
        float a = fmaxf(1.f - r * (1.f - sim), 0.f);
        int dc = min(max(d, 0), dmax);
        bool valid = (d >= 0) && (d <= dmax);
        att_lds[i_loc][jc] = valid ? a * a * soft_lds[dc] : 0.f;
    }
    __syncthreads();

    int wv = t >> 6, ihalf = (t >> 5) & 1, dvp = t & 31;
    int ib = wv * 8 + ihalf * 4;
    float acc[4][2] = {};

    for (int g4 = 0; g4 < g4_hi; ++g4) {
        int jc0 = g4 * 4;
        float4 am[4];
        #pragma unroll
        for (int m = 0; m < 4; ++m)
            am[m] = *(const float4*)&att_lds[ib + m][jc0];
        float2 v0 = *(const float2*)&V_lds[jc0 + 0][dvp * 2];
        float2 v1 = *(const float2*)&V_lds[jc0 + 1][dvp * 2];
        float2 v2 = *(const float2*)&V_lds[jc0 + 2][dvp * 2];
        float2 v3 = *(const float2*)&V_lds[jc0 + 3][dvp * 2];
        #pragma unroll
        for (int m = 0; m < 4; ++m) {
            acc[m][0] += am[m].x * v0.x + am[m].y * v1.x
                       + am[m].z * v2.x + am[m].w * v3.x;
            acc[m][1] += am[m].x * v0.y + am[m].y * v1.y
                       + am[m].z * v2.y + am[m].w * v3.y;
        }
    }

    if (nch == 1) {
        float hs = expf(log_hscale[h]);
        #pragma unroll
        for (int m = 0; m < 4; ++m) {
            float ss = acc[m][0]*acc[m][0] + acc[m][1]*acc[m][1];
            #pragma unroll
            for (int off = 16; off; off >>= 1) ss += __shfl_xor(ss, off);
            float norm = sqrtf(ss);
            float scale = tanhf(norm) / fmaxf(norm, 1e-12f);
            int i = i0 + ib + m;
            float2 g2 = *(const float2*)(qg + (size_t)i * QGN + h * QGW + DKQ + dvp * 2);
            float gate0 = tanhf(g2.x / (1.f + expf(-g2.x)));
            float gate1 = tanhf(g2.y / (1.f + expf(-g2.y)));
            __hip_bfloat16 ob[2] = { __float2bfloat16(acc[m][0] * scale * gate0 * hs),
                                     __float2bfloat16(acc[m][1] * scale * gate1 * hs) };
            *(ushort2*)(Yb + (size_t)i * HD + h * DVH + dvp * 2) = *(const ushort2*)ob;
        }
    } else {
        #pragma unroll
        for (int m = 0; m < 4; ++m) {
            int i = i0 + ib + m;
            float2 st = make_float2(acc[m][0], acc[m][1]);
            *(float2*)(Ypart + ((size_t)slot * N_TOK + i) * HD + h * DVH + dvp * 2) = st;
        }
    }
}

// ---------------------------------------------------------------------------
// Epilogue for multi-chunk rows only (h in {5,6,7}). One wave per (h, i).
// ---------------------------------------------------------------------------
__global__ __launch_bounds__(256) void attn_epilogue_kernel(
    const float* __restrict__ Ypart, const float* __restrict__ qg,
    const float* __restrict__ log_window, const float* __restrict__ log_hscale,
    __hip_bfloat16* __restrict__ Y)
{
    int wv = threadIdx.x >> 6, lane = threadIdx.x & 63;
    int gid = 5 * N_TOK + blockIdx.x * 4 + wv;   // h*N_TOK + i
    int h = gid >> 12;
    int i = gid & (N_TOK - 1);

    float w  = expf(log_window[h]) + 1.f;
    int dmax = (int)ceilf(w) - 1;
    int i0 = i & ~(TI - 1);
    int jstart = i0 - dmax; if (jstart < 0) jstart = 0;
    int nch = (i0 + TI - jstart + DC - 1) / DC;
    if (nch < 2) return;

    float hs = expf(log_hscale[h]);
    size_t base = (size_t)i * HD + h * DVH + lane;
    float a = 0.f;
    for (int c = 0; c < nch; ++c)
        a += Ypart[(size_t)c * N_TOK * HD + base];

    float g = qg[(size_t)i * QGN + h * QGW + DKQ + lane];
    float gate = tanhf(g / (1.f + expf(-g)));

    float ss = a * a;
    #pragma unroll
    for (int off = 32; off; off >>= 1) ss += __shfl_xor(ss, off);
    float norm = sqrtf(ss);
    float scale = tanhf(norm) / fmaxf(norm, 1e-12f);

    float o = a * scale * gate * hs;
    Y[(size_t)i * HD + h * DVH + lane] = __float2bfloat16(o);
}

// ---------------------------------------------------------------------------
extern "C" void kernel_launch(void* const* d_in, const int* in_sizes, int n_in,
                              void* d_out, int out_size, void* d_ws, size_t ws_size,
                              hipStream_t stream)
{
    const float* tokens     = (const float*)d_in[0];
    const float* w_qg       = (const float*)d_in[1];
    const float* w_kv       = (const float*)d_in[2];
    const float* w_out      = (const float*)d_in[3];
    const float* log_window = (const float*)d_in[4];
    const float* log_r      = (const float*)d_in[5];
    const float* log_hscale = (const float*)d_in[6];
    float* out = (float*)d_out;

    char* ws = (char*)d_ws;
    float* qg = (float*)ws;            ws += (size_t)N_TOK * QGN * 4;
    float* kv = (float*)ws;            ws += (size_t)N_TOK * QGN * 4;
    __hip_bfloat16* tokB  = (__hip_bfloat16*)ws; ws += (size_t)N_TOK * D_MODEL * 2;
    __hip_bfloat16* wqgT  = (__hip_bfloat16*)ws; ws += (size_t)QGN * D_MODEL * 2;
    __hip_bfloat16* wkvT  = (__hip_bfloat16*)ws; ws += (size_t)QGN * D_MODEL * 2;
    __hip_bfloat16* woutT = (__hip_bfloat16*)ws; ws += (size_t)D_MODEL * HD * 2;
    __hip_bfloat16* Yb    = (__hip_bfloat16*)ws; ws += (size_t)N_TOK * HD * 2;
    float* Ypart = (float*)ws;         ws += (size_t)NCH_MAX * N_TOK * HD * 4;

    // 0) pack: tokens cast (grid-stride) + weight transposes
    pack_kernel<<<2816, 256, 0, stream>>>(tokens, w_qg, w_kv, w_out,
                                          tokB, wqgT, wkvT, woutT);
    // 1) qg / kv projection (dual-B, BN=64 -> 640 blocks, XCD-swizzled)
    {
        dim3 grid(2 * (QGN / 64), N_TOK / 128);
        gemm_mfma<<<grid, 256, 0, stream>>>(tokB, wqgT, qg, wkvT, kv,
                                            QGN, D_MODEL, QGN / 64);
    }
    // 2) chunk-parallel attention (fused norm; fused epilogue when nch==1)
    attn_chunk_kernel<<<NHEAD * (N_TOK / TI) * NCH_MAX, 256, 0, stream>>>(
        qg, kv, log_window, log_r, log_hscale, Ypart, Yb);
    // 3) epilogue for multi-chunk rows
    attn_epilogue_kernel<<<EPI_UNITS, 256, 0, stream>>>(
        Ypart, qg, log_window, log_hscale, Yb);
    // 4) out = Y @ w_out (512 blocks, XCD-swizzled)
    {
        dim3 grid(D_MODEL / 64, N_TOK / 128);
        gemm_mfma<<<grid, 256, 0, stream>>>(Yb, woutT, out, woutT, out,
                                            D_MODEL, HD, D_MODEL / 64);
    }
}